// Round 1
// baseline (1954.597 us; speedup 1.0000x reference)
//
#include <hip/hip_runtime.h>

typedef __attribute__((ext_vector_type(8))) short short8;
typedef __attribute__((ext_vector_type(4))) float f32x4;

#define DI __device__ __forceinline__

constexpr int Bc = 4, Sc = 1025, Ec = 3200, NHc = 25, Dc = 128;
constexpr int Mc = Bc * Sc;          // 4100
constexpr int Mpad = 4160;           // 65 * 64
constexpr int N1c = 3 * Ec;          // 9600
constexpr int Spad = 1152;           // >= 1088 (Q reads) and >= 1056 (KV tiles), mult of 128
constexpr int BHc = Bc * NHc;        // 100
constexpr float ATTN_SCALE = 0.08838834764831845f;  // 128^-0.5

DI unsigned short f2bf(float f) {
  union { float f; unsigned u; } x; x.f = f;
  unsigned r = x.u + 0x7fffu + ((x.u >> 16) & 1u);   // RNE
  return (unsigned short)(r >> 16);
}
DI float bf2f(unsigned short h) {
  union { unsigned u; float f; } x; x.u = (unsigned)h << 16;
  return x.f;
}

// ---------------- int32 -> bf16 conversion (values are small ints, exact) ----
__global__ __launch_bounds__(256) void cvt_i32_bf16(const int* __restrict__ src,
                                                    unsigned short* __restrict__ dst, int n) {
  int i = (blockIdx.x * 256 + threadIdx.x) * 4;
  if (i >= n) return;
  int4 v = *(const int4*)(src + i);
  union { unsigned short us[4]; unsigned long long ll; } o;
  o.us[0] = f2bf((float)v.x);
  o.us[1] = f2bf((float)v.y);
  o.us[2] = f2bf((float)v.z);
  o.us[3] = f2bf((float)v.w);
  *(unsigned long long*)(dst + i) = o.ll;
}

// ---------------- shared 64x64 bf16 GEMM mainloop (C = A * Bt^T), K=3200 -----
// 4 waves as 2x2 grid of 32x32 sub-tiles; 16x16x32 bf16 MFMA.
DI void gemm64(const unsigned short* __restrict__ A, const unsigned short* __restrict__ Bt,
               int m0, int n0, f32x4 (&acc)[2][2],
               unsigned short (&As)[64][40], unsigned short (&Bs)[64][40]) {
  const int tid = threadIdx.x;
  const int lane = tid & 63, w = tid >> 6;
  const int r = lane & 15, g = lane >> 4;
  const int wm = (w >> 1) * 32, wn = (w & 1) * 32;
  const int sr = tid >> 2, sc = (tid & 3) * 8;
  const unsigned short* ap = A + (size_t)(m0 + sr) * Ec + sc;
  const unsigned short* bp = Bt + (size_t)(n0 + sr) * Ec + sc;
  for (int k0 = 0; k0 < Ec; k0 += 32) {
    __syncthreads();
    *(int4*)&As[sr][sc] = *(const int4*)(ap + k0);
    *(int4*)&Bs[sr][sc] = *(const int4*)(bp + k0);
    __syncthreads();
    short8 a0 = *(const short8*)&As[wm + r][g * 8];
    short8 a1 = *(const short8*)&As[wm + 16 + r][g * 8];
    short8 b0 = *(const short8*)&Bs[wn + r][g * 8];
    short8 b1 = *(const short8*)&Bs[wn + 16 + r][g * 8];
    acc[0][0] = __builtin_amdgcn_mfma_f32_16x16x32_bf16(a0, b0, acc[0][0], 0, 0, 0);
    acc[0][1] = __builtin_amdgcn_mfma_f32_16x16x32_bf16(a0, b1, acc[0][1], 0, 0, 0);
    acc[1][0] = __builtin_amdgcn_mfma_f32_16x16x32_bf16(a1, b0, acc[1][0], 0, 0, 0);
    acc[1][1] = __builtin_amdgcn_mfma_f32_16x16x32_bf16(a1, b1, acc[1][1], 0, 0, 0);
  }
}

// ---------------- kernel 1: QKV GEMM + scale/bias + scatter to Q/K/V ---------
__global__ __launch_bounds__(256) void gemm_qkv(
    const unsigned short* __restrict__ Xbf, const unsigned short* __restrict__ Wq,
    const float* __restrict__ qsc, const float* __restrict__ qkvs, const float* __restrict__ qkvb,
    float* __restrict__ Qf, unsigned short* __restrict__ Khi, unsigned short* __restrict__ Klo,
    unsigned short* __restrict__ Vt) {
  __shared__ unsigned short As[64][40];
  __shared__ unsigned short Bs[64][40];
  f32x4 acc[2][2];
#pragma unroll
  for (int i = 0; i < 2; ++i)
#pragma unroll
    for (int j = 0; j < 2; ++j)
#pragma unroll
      for (int k = 0; k < 4; ++k) acc[i][j][k] = 0.f;
  const int m0 = blockIdx.y * 64, n0 = blockIdx.x * 64;
  gemm64(Xbf, Wq, m0, n0, acc, As, Bs);

  const int lane = threadIdx.x & 63, w = threadIdx.x >> 6;
  const int r = lane & 15, g = lane >> 4;
  const int wm = (w >> 1) * 32, wn = (w & 1) * 32;
  const int which = n0 / Ec;   // uniform per block (E % 64 == 0)
#pragma unroll
  for (int mi = 0; mi < 2; ++mi)
#pragma unroll
    for (int ni = 0; ni < 2; ++ni)
#pragma unroll
      for (int j = 0; j < 4; ++j) {
        int row = m0 + wm + mi * 16 + g * 4 + j;
        if (row >= Mc) continue;
        int col = n0 + wn + ni * 16 + r;
        float v = acc[mi][ni][j] * qsc[row] * qkvs[col] + qkvb[col];
        int bb = row / Sc, ss = row - bb * Sc;
        int ce = col - which * Ec;
        int hh = ce >> 7, dd = ce & 127;
        size_t bh = (size_t)(bb * NHc + hh);
        if (which == 0) {
          Qf[(bh * Spad + ss) * Dc + dd] = v;
        } else if (which == 1) {
          unsigned short hi = f2bf(v);
          unsigned short lo = f2bf(v - bf2f(hi));
          size_t idx = (bh * Spad + ss) * Dc + dd;
          Khi[idx] = hi;
          Klo[idx] = lo;
        } else {
          Vt[(bh * Dc + dd) * Spad + ss] = f2bf(v);
        }
      }
}

// ---------------- kernel 2: flash attention -------------------------------
// block = 4 waves; wave w handles 16 q rows; one (b,h) per blockIdx.y.
__global__ __launch_bounds__(256) void attn_kernel(
    const float* __restrict__ Qf, const unsigned short* __restrict__ Khi,
    const unsigned short* __restrict__ Klo, const unsigned short* __restrict__ Vt,
    float* __restrict__ Out) {
  __shared__ unsigned short Pl[4][16][40];
  const int tid = threadIdx.x, lane = tid & 63, w = tid >> 6;
  const int r = lane & 15, g = lane >> 4;
  const int bh = blockIdx.y, qb = blockIdx.x;
  const int b = bh / NHc, h = bh - b * NHc;
  const float* Qb = Qf + (size_t)bh * Spad * Dc;
  const unsigned short* Khb = Khi + (size_t)bh * Spad * Dc;
  const unsigned short* Klb = Klo + (size_t)bh * Spad * Dc;
  const unsigned short* Vb = Vt + (size_t)bh * Dc * Spad;
  const int q0 = qb * 64 + w * 16;

  // hoist Q (scaled) as hi/lo bf16 fragments
  short8 qhi[4], qlo[4];
  {
    const float* qp = Qb + (size_t)(q0 + r) * Dc + g * 8;
#pragma unroll
    for (int kf = 0; kf < 4; ++kf) {
      float4 v0 = *(const float4*)(qp + kf * 32);
      float4 v1 = *(const float4*)(qp + kf * 32 + 4);
      float f[8] = {v0.x, v0.y, v0.z, v0.w, v1.x, v1.y, v1.z, v1.w};
#pragma unroll
      for (int j = 0; j < 8; ++j) {
        float s = f[j] * ATTN_SCALE;
        unsigned short hi = f2bf(s);
        qhi[kf][j] = (short)hi;
        qlo[kf][j] = (short)f2bf(s - bf2f(hi));
      }
    }
  }

  f32x4 accO[8];
#pragma unroll
  for (int df = 0; df < 8; ++df)
#pragma unroll
    for (int j = 0; j < 4; ++j) accO[df][j] = 0.f;
  float m_run[4], l_run[4];
#pragma unroll
  for (int j = 0; j < 4; ++j) { m_run[j] = -INFINITY; l_run[j] = 0.f; }

  for (int t0 = 0; t0 < 1056; t0 += 32) {
    f32x4 sacc[2];
#pragma unroll
    for (int nb = 0; nb < 2; ++nb)
#pragma unroll
      for (int j = 0; j < 4; ++j) sacc[nb][j] = 0.f;

#pragma unroll
    for (int nb = 0; nb < 2; ++nb) {
      const int tr = t0 + nb * 16 + r;
      const unsigned short* kh = Khb + (size_t)tr * Dc + g * 8;
      const unsigned short* kl = Klb + (size_t)tr * Dc + g * 8;
#pragma unroll
      for (int kf = 0; kf < 4; ++kf) {
        short8 bh_ = *(const short8*)(kh + kf * 32);
        short8 bl_ = *(const short8*)(kl + kf * 32);
        sacc[nb] = __builtin_amdgcn_mfma_f32_16x16x32_bf16(qhi[kf], bh_, sacc[nb], 0, 0, 0);
        sacc[nb] = __builtin_amdgcn_mfma_f32_16x16x32_bf16(qlo[kf], bh_, sacc[nb], 0, 0, 0);
        sacc[nb] = __builtin_amdgcn_mfma_f32_16x16x32_bf16(qhi[kf], bl_, sacc[nb], 0, 0, 0);
      }
      if (tr >= Sc) {
#pragma unroll
        for (int j = 0; j < 4; ++j) sacc[nb][j] = -1e30f;
      }
    }

    // online softmax: rows are (g*4+j); reduce across the 16-lane group
    float mt[4];
#pragma unroll
    for (int j = 0; j < 4; ++j) mt[j] = fmaxf(sacc[0][j], sacc[1][j]);
#pragma unroll
    for (int d = 1; d < 16; d <<= 1)
#pragma unroll
      for (int j = 0; j < 4; ++j) mt[j] = fmaxf(mt[j], __shfl_xor(mt[j], d, 64));
    float p0[4], p1[4], ps[4], resc[4];
#pragma unroll
    for (int j = 0; j < 4; ++j) {
      float mn = fmaxf(m_run[j], mt[j]);
      resc[j] = __expf(m_run[j] - mn);
      m_run[j] = mn;
      p0[j] = __expf(sacc[0][j] - mn);
      p1[j] = __expf(sacc[1][j] - mn);
      ps[j] = p0[j] + p1[j];
    }
#pragma unroll
    for (int d = 1; d < 16; d <<= 1)
#pragma unroll
      for (int j = 0; j < 4; ++j) ps[j] += __shfl_xor(ps[j], d, 64);
#pragma unroll
    for (int j = 0; j < 4; ++j) l_run[j] = l_run[j] * resc[j] + ps[j];
#pragma unroll
    for (int df = 0; df < 8; ++df)
#pragma unroll
      for (int j = 0; j < 4; ++j) accO[df][j] *= resc[j];

    // transpose P (C-layout -> A-layout) through LDS
    __syncthreads();
#pragma unroll
    for (int j = 0; j < 4; ++j) {
      Pl[w][g * 4 + j][r] = f2bf(p0[j]);
      Pl[w][g * 4 + j][16 + r] = f2bf(p1[j]);
    }
    __syncthreads();
    short8 pa = *(const short8*)&Pl[w][r][g * 8];
#pragma unroll
    for (int df = 0; df < 8; ++df) {
      const unsigned short* vp = Vb + (size_t)(df * 16 + r) * Spad + t0 + g * 8;
      short8 vb_ = *(const short8*)vp;
      accO[df] = __builtin_amdgcn_mfma_f32_16x16x32_bf16(pa, vb_, accO[df], 0, 0, 0);
    }
  }

  // epilogue: divide by l, store to Out[m][h*128+d]
#pragma unroll
  for (int j = 0; j < 4; ++j) {
    int sr_ = q0 + g * 4 + j;
    if (sr_ < Sc) {
      float inv = 1.f / l_run[j];
      float* op = Out + ((size_t)(b * Sc + sr_)) * Ec + h * Dc + r;
#pragma unroll
      for (int df = 0; df < 8; ++df) op[df * 16] = accO[df][j] * inv;
    }
  }
}

// ---------------- kernel 3: per-row absmax + quantize ------------------------
__global__ __launch_bounds__(256) void rowquant(const float* __restrict__ Out,
                                                unsigned short* __restrict__ Q2,
                                                float* __restrict__ S2v) {
  const int m = blockIdx.x;
  const int t = threadIdx.x;
  const float* row = Out + (size_t)m * Ec;
  float am = 0.f;
  for (int i = t * 4; i < Ec; i += 1024) {
    float4 v = *(const float4*)(row + i);
    am = fmaxf(am, fmaxf(fmaxf(fabsf(v.x), fabsf(v.y)), fmaxf(fabsf(v.z), fabsf(v.w))));
  }
#pragma unroll
  for (int d = 1; d < 64; d <<= 1) am = fmaxf(am, __shfl_xor(am, d, 64));
  __shared__ float red[4];
  if ((t & 63) == 0) red[t >> 6] = am;
  __syncthreads();
  am = fmaxf(fmaxf(red[0], red[1]), fmaxf(red[2], red[3]));
  float s2 = am / 127.f;
  if (!(s2 > 0.f)) s2 = 1.f;
  for (int i = t * 4; i < Ec; i += 1024) {
    float4 v = *(const float4*)(row + i);
    ushort4 q;
    q.x = f2bf(fminf(127.f, fmaxf(-128.f, rintf(v.x / s2))));
    q.y = f2bf(fminf(127.f, fmaxf(-128.f, rintf(v.y / s2))));
    q.z = f2bf(fminf(127.f, fmaxf(-128.f, rintf(v.z / s2))));
    q.w = f2bf(fminf(127.f, fmaxf(-128.f, rintf(v.w / s2))));
    *(ushort4*)(Q2 + (size_t)m * Ec + i) = q;
  }
  if (t == 0) S2v[m] = s2;
}

// ---------------- kernel 4: proj GEMM + scale/bias ---------------------------
__global__ __launch_bounds__(256) void gemm_proj(
    const unsigned short* __restrict__ Q2, const unsigned short* __restrict__ Wp,
    const float* __restrict__ S2v, const float* __restrict__ ps, const float* __restrict__ pb,
    float* __restrict__ Y) {
  __shared__ unsigned short As[64][40];
  __shared__ unsigned short Bs[64][40];
  f32x4 acc[2][2];
#pragma unroll
  for (int i = 0; i < 2; ++i)
#pragma unroll
    for (int j = 0; j < 2; ++j)
#pragma unroll
      for (int k = 0; k < 4; ++k) acc[i][j][k] = 0.f;
  const int m0 = blockIdx.y * 64, n0 = blockIdx.x * 64;
  gemm64(Q2, Wp, m0, n0, acc, As, Bs);

  const int lane = threadIdx.x & 63, w = threadIdx.x >> 6;
  const int r = lane & 15, g = lane >> 4;
  const int wm = (w >> 1) * 32, wn = (w & 1) * 32;
#pragma unroll
  for (int mi = 0; mi < 2; ++mi)
#pragma unroll
    for (int ni = 0; ni < 2; ++ni)
#pragma unroll
      for (int j = 0; j < 4; ++j) {
        int row = m0 + wm + mi * 16 + g * 4 + j;
        if (row >= Mc) continue;
        int col = n0 + wn + ni * 16 + r;
        Y[(size_t)row * Ec + col] = acc[mi][ni][j] * S2v[row] * ps[col] + pb[col];
      }
}

// ---------------- launch -----------------------------------------------------
extern "C" void kernel_launch(void* const* d_in, const int* in_sizes, int n_in,
                              void* d_out, int out_size, void* d_ws, size_t ws_size,
                              hipStream_t stream) {
  const int* hs = (const int*)d_in[0];
  const float* qscale = (const float*)d_in[1];
  const int* qkvw = (const int*)d_in[2];
  const float* qkvs = (const float*)d_in[3];
  const float* qkvb = (const float*)d_in[4];
  const int* projw = (const int*)d_in[5];
  const float* projs = (const float*)d_in[6];
  const float* projb = (const float*)d_in[7];
  float* y = (float*)d_out;

  char* p = (char*)d_ws;
  auto carve = [&](size_t bytes) {
    char* q = p;
    p += (bytes + 255) & ~(size_t)255;
    return q;
  };
  unsigned short* Xbf = (unsigned short*)carve((size_t)Mpad * Ec * 2);   // 26.6 MB
  unsigned short* Wq = (unsigned short*)carve((size_t)N1c * Ec * 2);     // 61.4 MB
  unsigned short* Wp = (unsigned short*)carve((size_t)Ec * Ec * 2);      // 20.5 MB
  float* Qf = (float*)carve((size_t)BHc * Spad * Dc * 4);                // 59.0 MB
  unsigned short* Khi = (unsigned short*)carve((size_t)BHc * Spad * Dc * 2);  // 29.5 MB
  unsigned short* Klo = (unsigned short*)carve((size_t)BHc * Spad * Dc * 2);  // 29.5 MB
  unsigned short* Vt = (unsigned short*)carve((size_t)BHc * Dc * Spad * 2);   // 29.5 MB
  // aliases: Wq region is dead after gemm_qkv -> reuse for attention output;
  // Xbf region is dead after gemm_qkv -> reuse for Q2 (pad rows stay zero).
  float* Out = (float*)Wq;           // needs 52.5 MB <= 61.4 MB
  unsigned short* Q2 = Xbf;          // same size/padding semantics
  float* S2v = (float*)carve((size_t)Mpad * 4);

  // zero the padding rows of Xbf (also serves as Q2's padding later)
  hipMemsetAsync(Xbf + (size_t)Mc * Ec, 0, (size_t)(Mpad - Mc) * Ec * 2, stream);

  cvt_i32_bf16<<<(Mc * Ec / 4 + 255) / 256, 256, 0, stream>>>(hs, Xbf, Mc * Ec);
  cvt_i32_bf16<<<(N1c * Ec / 4) / 256, 256, 0, stream>>>(qkvw, Wq, N1c * Ec);
  cvt_i32_bf16<<<(Ec * Ec / 4) / 256, 256, 0, stream>>>(projw, Wp, Ec * Ec);

  gemm_qkv<<<dim3(N1c / 64, Mpad / 64), 256, 0, stream>>>(Xbf, Wq, qscale, qkvs, qkvb,
                                                          Qf, Khi, Klo, Vt);
  attn_kernel<<<dim3(17, BHc), 256, 0, stream>>>(Qf, Khi, Klo, Vt, Out);
  rowquant<<<Mc, 256, 0, stream>>>(Out, Q2, S2v);
  gemm_proj<<<dim3(Ec / 64, Mpad / 64), 256, 0, stream>>>(Q2, Wp, S2v, projs, projb, y);
}

// Round 2
// 1642.064 us; speedup vs baseline: 1.1903x; 1.1903x over previous
//
#include <hip/hip_runtime.h>

typedef __attribute__((ext_vector_type(8))) short short8;
typedef __attribute__((ext_vector_type(4))) float f32x4;

#define DI __device__ __forceinline__

constexpr int Bc = 4, Sc = 1025, Ec = 3200, NHc = 25, Dc = 128;
constexpr int Mc = Bc * Sc;          // 4100
constexpr int Mpad = 4224;           // 33 * 128
constexpr int N1c = 3 * Ec;          // 9600
constexpr int Spad = 1152;           // >= 1088 (Q reads) and >= 1056 (KV tiles), mult of 128
constexpr int BHc = Bc * NHc;        // 100
constexpr float ATTN_SCALE = 0.08838834764831845f;  // 128^-0.5

DI unsigned short f2bf(float f) {
  union { float f; unsigned u; } x; x.f = f;
  unsigned r = x.u + 0x7fffu + ((x.u >> 16) & 1u);   // RNE
  return (unsigned short)(r >> 16);
}
DI float bf2f(unsigned short h) {
  union { unsigned u; float f; } x; x.u = (unsigned)h << 16;
  return x.f;
}

// async global->LDS, 16B per lane; LDS dest = wave-uniform base + lane*16 (linear)
DI void gl_lds16(const void* g, void* l) {
  __builtin_amdgcn_global_load_lds(
      (const __attribute__((address_space(1))) unsigned int*)g,
      (__attribute__((address_space(3))) unsigned int*)l, 16, 0, 0);
}

// ---------------- int32 -> bf16 conversion (values are small ints, exact) ----
__global__ __launch_bounds__(256) void cvt_i32_bf16(const int* __restrict__ src,
                                                    unsigned short* __restrict__ dst, int n) {
  int i = (blockIdx.x * 256 + threadIdx.x) * 4;
  if (i >= n) return;
  int4 v = *(const int4*)(src + i);
  union { unsigned short us[4]; unsigned long long ll; } o;
  o.us[0] = f2bf((float)v.x);
  o.us[1] = f2bf((float)v.y);
  o.us[2] = f2bf((float)v.z);
  o.us[3] = f2bf((float)v.w);
  *(unsigned long long*)(dst + i) = o.ll;
}

// ---------------- 128x128 bf16 GEMM mainloop (m97 structure) -----------------
// C = A * Bt^T over K=3200. 4 waves as 2x2 grid of 64x64 sub-tiles; BK=32;
// staging via global_load_lds width-16 (linear LDS, 2 issues/wave/operand).
DI void gemm128(const unsigned short* __restrict__ A, const unsigned short* __restrict__ Bt,
                int m0, int n0, f32x4 (&acc)[4][4],
                unsigned short (&As)[128][32], unsigned short (&Bs)[128][32]) {
  const int tid = threadIdx.x;
  const int lane = tid & 63, w = tid >> 6;
  const int r = lane & 15, g = lane >> 4;
  const int wm = (w >> 1) * 64, wn = (w & 1) * 64;
  // staging geometry: wave w covers rows [w*32, w*32+32) of the tile, 16 rows/issue
  const int lrow = lane >> 2, lcol = (lane & 3) * 8;
  const unsigned short* ag = A + (size_t)(m0 + w * 32 + lrow) * Ec + lcol;
  const unsigned short* bg = Bt + (size_t)(n0 + w * 32 + lrow) * Ec + lcol;
  unsigned short* la0 = &As[w * 32][0];
  unsigned short* la1 = &As[w * 32 + 16][0];
  unsigned short* lb0 = &Bs[w * 32][0];
  unsigned short* lb1 = &Bs[w * 32 + 16][0];

  for (int k0 = 0; k0 < Ec; k0 += 32) {
    __syncthreads();                       // all waves done reading prev tile
    gl_lds16(ag + k0, la0);
    gl_lds16(ag + (size_t)16 * Ec + k0, la1);
    gl_lds16(bg + k0, lb0);
    gl_lds16(bg + (size_t)16 * Ec + k0, lb1);
    __syncthreads();                       // drains vmcnt(0) -> LDS ready
    short8 af[4], bf[4];
#pragma unroll
    for (int mi = 0; mi < 4; ++mi) af[mi] = *(const short8*)&As[wm + mi * 16 + r][g * 8];
#pragma unroll
    for (int ni = 0; ni < 4; ++ni) bf[ni] = *(const short8*)&Bs[wn + ni * 16 + r][g * 8];
#pragma unroll
    for (int mi = 0; mi < 4; ++mi)
#pragma unroll
      for (int ni = 0; ni < 4; ++ni)
        acc[mi][ni] = __builtin_amdgcn_mfma_f32_16x16x32_bf16(af[mi], bf[ni], acc[mi][ni], 0, 0, 0);
  }
}

// ---------------- kernel 1: QKV GEMM + scale/bias + scatter to Q/K/V ---------
__global__ __launch_bounds__(256) void gemm_qkv(
    const unsigned short* __restrict__ Xbf, const unsigned short* __restrict__ Wq,
    const float* __restrict__ qsc, const float* __restrict__ qkvs, const float* __restrict__ qkvb,
    float* __restrict__ Qf, unsigned short* __restrict__ Khi, unsigned short* __restrict__ Klo,
    unsigned short* __restrict__ Vt) {
  __shared__ __align__(16) unsigned short As[128][32];
  __shared__ __align__(16) unsigned short Bs[128][32];
  f32x4 acc[4][4];
#pragma unroll
  for (int i = 0; i < 4; ++i)
#pragma unroll
    for (int j = 0; j < 4; ++j)
#pragma unroll
      for (int k = 0; k < 4; ++k) acc[i][j][k] = 0.f;
  const int m0 = blockIdx.y * 128, n0 = blockIdx.x * 128;
  gemm128(Xbf, Wq, m0, n0, acc, As, Bs);

  const int lane = threadIdx.x & 63, w = threadIdx.x >> 6;
  const int r = lane & 15, g = lane >> 4;
  const int wm = (w >> 1) * 64, wn = (w & 1) * 64;
  const int which = n0 / Ec;   // uniform per block (Ec % 128 == 0)
#pragma unroll
  for (int mi = 0; mi < 4; ++mi)
#pragma unroll
    for (int ni = 0; ni < 4; ++ni)
#pragma unroll
      for (int j = 0; j < 4; ++j) {
        int row = m0 + wm + mi * 16 + g * 4 + j;
        if (row >= Mc) continue;
        int col = n0 + wn + ni * 16 + r;
        float v = acc[mi][ni][j] * qsc[row] * qkvs[col] + qkvb[col];
        int bb = row / Sc, ss = row - bb * Sc;
        int ce = col - which * Ec;
        int hh = ce >> 7, dd = ce & 127;
        size_t bh = (size_t)(bb * NHc + hh);
        if (which == 0) {
          Qf[(bh * Spad + ss) * Dc + dd] = v;
        } else if (which == 1) {
          unsigned short hi = f2bf(v);
          unsigned short lo = f2bf(v - bf2f(hi));
          size_t idx = (bh * Spad + ss) * Dc + dd;
          Khi[idx] = hi;
          Klo[idx] = lo;
        } else {
          Vt[(bh * Dc + dd) * Spad + ss] = f2bf(v);
        }
      }
}

// ---------------- kernel 2: flash attention -------------------------------
// block = 4 waves; wave w handles 16 q rows; one (b,h) per blockIdx.y.
__global__ __launch_bounds__(256) void attn_kernel(
    const float* __restrict__ Qf, const unsigned short* __restrict__ Khi,
    const unsigned short* __restrict__ Klo, const unsigned short* __restrict__ Vt,
    float* __restrict__ Out) {
  __shared__ unsigned short Pl[4][16][40];
  const int tid = threadIdx.x, lane = tid & 63, w = tid >> 6;
  const int r = lane & 15, g = lane >> 4;
  const int bh = blockIdx.y, qb = blockIdx.x;
  const int b = bh / NHc, h = bh - b * NHc;
  const float* Qb = Qf + (size_t)bh * Spad * Dc;
  const unsigned short* Khb = Khi + (size_t)bh * Spad * Dc;
  const unsigned short* Klb = Klo + (size_t)bh * Spad * Dc;
  const unsigned short* Vb = Vt + (size_t)bh * Dc * Spad;
  const int q0 = qb * 64 + w * 16;

  // hoist Q (scaled) as hi/lo bf16 fragments
  short8 qhi[4], qlo[4];
  {
    const float* qp = Qb + (size_t)(q0 + r) * Dc + g * 8;
#pragma unroll
    for (int kf = 0; kf < 4; ++kf) {
      float4 v0 = *(const float4*)(qp + kf * 32);
      float4 v1 = *(const float4*)(qp + kf * 32 + 4);
      float f[8] = {v0.x, v0.y, v0.z, v0.w, v1.x, v1.y, v1.z, v1.w};
#pragma unroll
      for (int j = 0; j < 8; ++j) {
        float s = f[j] * ATTN_SCALE;
        unsigned short hi = f2bf(s);
        qhi[kf][j] = (short)hi;
        qlo[kf][j] = (short)f2bf(s - bf2f(hi));
      }
    }
  }

  f32x4 accO[8];
#pragma unroll
  for (int df = 0; df < 8; ++df)
#pragma unroll
    for (int j = 0; j < 4; ++j) accO[df][j] = 0.f;
  float m_run[4], l_run[4];
#pragma unroll
  for (int j = 0; j < 4; ++j) { m_run[j] = -INFINITY; l_run[j] = 0.f; }

  for (int t0 = 0; t0 < 1056; t0 += 32) {
    f32x4 sacc[2];
#pragma unroll
    for (int nb = 0; nb < 2; ++nb)
#pragma unroll
      for (int j = 0; j < 4; ++j) sacc[nb][j] = 0.f;

#pragma unroll
    for (int nb = 0; nb < 2; ++nb) {
      const int tr = t0 + nb * 16 + r;
      const unsigned short* kh = Khb + (size_t)tr * Dc + g * 8;
      const unsigned short* kl = Klb + (size_t)tr * Dc + g * 8;
#pragma unroll
      for (int kf = 0; kf < 4; ++kf) {
        short8 bh_ = *(const short8*)(kh + kf * 32);
        short8 bl_ = *(const short8*)(kl + kf * 32);
        sacc[nb] = __builtin_amdgcn_mfma_f32_16x16x32_bf16(qhi[kf], bh_, sacc[nb], 0, 0, 0);
        sacc[nb] = __builtin_amdgcn_mfma_f32_16x16x32_bf16(qlo[kf], bh_, sacc[nb], 0, 0, 0);
        sacc[nb] = __builtin_amdgcn_mfma_f32_16x16x32_bf16(qhi[kf], bl_, sacc[nb], 0, 0, 0);
      }
      if (tr >= Sc) {
#pragma unroll
        for (int j = 0; j < 4; ++j) sacc[nb][j] = -1e30f;
      }
    }

    // online softmax: rows are (g*4+j); reduce across the 16-lane group
    float mt[4];
#pragma unroll
    for (int j = 0; j < 4; ++j) mt[j] = fmaxf(sacc[0][j], sacc[1][j]);
#pragma unroll
    for (int d = 1; d < 16; d <<= 1)
#pragma unroll
      for (int j = 0; j < 4; ++j) mt[j] = fmaxf(mt[j], __shfl_xor(mt[j], d, 64));
    float p0[4], p1[4], ps[4], resc[4];
#pragma unroll
    for (int j = 0; j < 4; ++j) {
      float mn = fmaxf(m_run[j], mt[j]);
      resc[j] = __expf(m_run[j] - mn);
      m_run[j] = mn;
      p0[j] = __expf(sacc[0][j] - mn);
      p1[j] = __expf(sacc[1][j] - mn);
      ps[j] = p0[j] + p1[j];
    }
#pragma unroll
    for (int d = 1; d < 16; d <<= 1)
#pragma unroll
      for (int j = 0; j < 4; ++j) ps[j] += __shfl_xor(ps[j], d, 64);
#pragma unroll
    for (int j = 0; j < 4; ++j) l_run[j] = l_run[j] * resc[j] + ps[j];
#pragma unroll
    for (int df = 0; df < 8; ++df)
#pragma unroll
      for (int j = 0; j < 4; ++j) accO[df][j] *= resc[j];

    // transpose P (C-layout -> A-layout) through LDS
    __syncthreads();
#pragma unroll
    for (int j = 0; j < 4; ++j) {
      Pl[w][g * 4 + j][r] = f2bf(p0[j]);
      Pl[w][g * 4 + j][16 + r] = f2bf(p1[j]);
    }
    __syncthreads();
    short8 pa = *(const short8*)&Pl[w][r][g * 8];
#pragma unroll
    for (int df = 0; df < 8; ++df) {
      const unsigned short* vp = Vb + (size_t)(df * 16 + r) * Spad + t0 + g * 8;
      short8 vb_ = *(const short8*)vp;
      accO[df] = __builtin_amdgcn_mfma_f32_16x16x32_bf16(pa, vb_, accO[df], 0, 0, 0);
    }
  }

  // epilogue: divide by l, store to Out[m][h*128+d]
#pragma unroll
  for (int j = 0; j < 4; ++j) {
    int sr_ = q0 + g * 4 + j;
    if (sr_ < Sc) {
      float inv = 1.f / l_run[j];
      float* op = Out + ((size_t)(b * Sc + sr_)) * Ec + h * Dc + r;
#pragma unroll
      for (int df = 0; df < 8; ++df) op[df * 16] = accO[df][j] * inv;
    }
  }
}

// ---------------- kernel 3: per-row absmax + quantize ------------------------
__global__ __launch_bounds__(256) void rowquant(const float* __restrict__ Out,
                                                unsigned short* __restrict__ Q2,
                                                float* __restrict__ S2v) {
  const int m = blockIdx.x;
  const int t = threadIdx.x;
  const float* row = Out + (size_t)m * Ec;
  float am = 0.f;
  for (int i = t * 4; i < Ec; i += 1024) {
    float4 v = *(const float4*)(row + i);
    am = fmaxf(am, fmaxf(fmaxf(fabsf(v.x), fabsf(v.y)), fmaxf(fabsf(v.z), fabsf(v.w))));
  }
#pragma unroll
  for (int d = 1; d < 64; d <<= 1) am = fmaxf(am, __shfl_xor(am, d, 64));
  __shared__ float red[4];
  if ((t & 63) == 0) red[t >> 6] = am;
  __syncthreads();
  am = fmaxf(fmaxf(red[0], red[1]), fmaxf(red[2], red[3]));
  float s2 = am / 127.f;
  if (!(s2 > 0.f)) s2 = 1.f;
  for (int i = t * 4; i < Ec; i += 1024) {
    float4 v = *(const float4*)(row + i);
    ushort4 q;
    q.x = f2bf(fminf(127.f, fmaxf(-128.f, rintf(v.x / s2))));
    q.y = f2bf(fminf(127.f, fmaxf(-128.f, rintf(v.y / s2))));
    q.z = f2bf(fminf(127.f, fmaxf(-128.f, rintf(v.z / s2))));
    q.w = f2bf(fminf(127.f, fmaxf(-128.f, rintf(v.w / s2))));
    *(ushort4*)(Q2 + (size_t)m * Ec + i) = q;
  }
  if (t == 0) S2v[m] = s2;
}

// ---------------- kernel 4: proj GEMM + scale/bias ---------------------------
__global__ __launch_bounds__(256) void gemm_proj(
    const unsigned short* __restrict__ Q2, const unsigned short* __restrict__ Wp,
    const float* __restrict__ S2v, const float* __restrict__ ps, const float* __restrict__ pb,
    float* __restrict__ Y) {
  __shared__ __align__(16) unsigned short As[128][32];
  __shared__ __align__(16) unsigned short Bs[128][32];
  f32x4 acc[4][4];
#pragma unroll
  for (int i = 0; i < 4; ++i)
#pragma unroll
    for (int j = 0; j < 4; ++j)
#pragma unroll
      for (int k = 0; k < 4; ++k) acc[i][j][k] = 0.f;
  const int m0 = blockIdx.y * 128, n0 = blockIdx.x * 128;
  gemm128(Q2, Wp, m0, n0, acc, As, Bs);

  const int lane = threadIdx.x & 63, w = threadIdx.x >> 6;
  const int r = lane & 15, g = lane >> 4;
  const int wm = (w >> 1) * 64, wn = (w & 1) * 64;
#pragma unroll
  for (int mi = 0; mi < 4; ++mi)
#pragma unroll
    for (int ni = 0; ni < 4; ++ni)
#pragma unroll
      for (int j = 0; j < 4; ++j) {
        int row = m0 + wm + mi * 16 + g * 4 + j;
        if (row >= Mc) continue;
        int col = n0 + wn + ni * 16 + r;
        Y[(size_t)row * Ec + col] = acc[mi][ni][j] * S2v[row] * ps[col] + pb[col];
      }
}

// ---------------- launch -----------------------------------------------------
extern "C" void kernel_launch(void* const* d_in, const int* in_sizes, int n_in,
                              void* d_out, int out_size, void* d_ws, size_t ws_size,
                              hipStream_t stream) {
  const int* hs = (const int*)d_in[0];
  const float* qscale = (const float*)d_in[1];
  const int* qkvw = (const int*)d_in[2];
  const float* qkvs = (const float*)d_in[3];
  const float* qkvb = (const float*)d_in[4];
  const int* projw = (const int*)d_in[5];
  const float* projs = (const float*)d_in[6];
  const float* projb = (const float*)d_in[7];
  float* y = (float*)d_out;

  char* p = (char*)d_ws;
  auto carve = [&](size_t bytes) {
    char* q = p;
    p += (bytes + 255) & ~(size_t)255;
    return q;
  };
  unsigned short* Xbf = (unsigned short*)carve((size_t)Mpad * Ec * 2);   // 27.0 MB
  unsigned short* Wq = (unsigned short*)carve((size_t)N1c * Ec * 2);     // 61.4 MB
  unsigned short* Wp = (unsigned short*)carve((size_t)Ec * Ec * 2);      // 20.5 MB
  float* Qf = (float*)carve((size_t)BHc * Spad * Dc * 4);                // 59.0 MB
  unsigned short* Khi = (unsigned short*)carve((size_t)BHc * Spad * Dc * 2);  // 29.5 MB
  unsigned short* Klo = (unsigned short*)carve((size_t)BHc * Spad * Dc * 2);  // 29.5 MB
  unsigned short* Vt = (unsigned short*)carve((size_t)BHc * Dc * Spad * 2);   // 29.5 MB
  // aliases: Wq region is dead after gemm_qkv -> reuse for attention output;
  // Xbf region is dead after gemm_qkv -> reuse for Q2 (pad rows stay zero).
  float* Out = (float*)Wq;           // needs 52.5 MB <= 61.4 MB
  unsigned short* Q2 = Xbf;          // same size/padding semantics
  float* S2v = (float*)carve((size_t)Mpad * 4);

  // zero the padding rows of Xbf (also serves as Q2's padding later)
  hipMemsetAsync(Xbf + (size_t)Mc * Ec, 0, (size_t)(Mpad - Mc) * Ec * 2, stream);

  cvt_i32_bf16<<<(Mc * Ec / 4 + 255) / 256, 256, 0, stream>>>(hs, Xbf, Mc * Ec);
  cvt_i32_bf16<<<(N1c * Ec / 4) / 256, 256, 0, stream>>>(qkvw, Wq, N1c * Ec);
  cvt_i32_bf16<<<(Ec * Ec / 4) / 256, 256, 0, stream>>>(projw, Wp, Ec * Ec);

  gemm_qkv<<<dim3(N1c / 128, Mpad / 128), 256, 0, stream>>>(Xbf, Wq, qscale, qkvs, qkvb,
                                                            Qf, Khi, Klo, Vt);
  attn_kernel<<<dim3(17, BHc), 256, 0, stream>>>(Qf, Khi, Klo, Vt, Out);
  rowquant<<<Mc, 256, 0, stream>>>(Out, Q2, S2v);
  gemm_proj<<<dim3(Ec / 128, Mpad / 128), 256, 0, stream>>>(Q2, Wp, S2v, projs, projb, y);
}

// Round 3
// 1234.467 us; speedup vs baseline: 1.5834x; 1.3302x over previous
//
#include <hip/hip_runtime.h>

typedef __attribute__((ext_vector_type(8))) short short8;
typedef __attribute__((ext_vector_type(4))) float f32x4;

#define DI __device__ __forceinline__

constexpr int Bc = 4, Sc = 1025, Ec = 3200, NHc = 25, Dc = 128;
constexpr int Mc = Bc * Sc;          // 4100
constexpr int Mpad = 4224;           // 33 * 128
constexpr int N1c = 3 * Ec;          // 9600
constexpr int Spad = 1152;           // >= 1088 (staging reads up to 1087) ; mult of 128
constexpr int BHc = Bc * NHc;        // 100
constexpr float ATTN_SCALE = 0.08838834764831845f;  // 128^-0.5

DI unsigned short f2bf(float f) {
  union { float f; unsigned u; } x; x.f = f;
  unsigned r = x.u + 0x7fffu + ((x.u >> 16) & 1u);   // RNE
  return (unsigned short)(r >> 16);
}
DI float bf2f(unsigned short h) {
  union { unsigned u; float f; } x; x.u = (unsigned)h << 16;
  return x.f;
}

// async global->LDS, 16B per lane; LDS dest = wave-uniform base + lane*16 (linear)
DI void gl_lds16(const void* g, void* l) {
  __builtin_amdgcn_global_load_lds(
      (const __attribute__((address_space(1))) unsigned int*)g,
      (__attribute__((address_space(3))) unsigned int*)l, 16, 0, 0);
}

// ---------------- int32 -> bf16 conversion (values are small ints, exact) ----
__global__ __launch_bounds__(256) void cvt_i32_bf16(const int* __restrict__ src,
                                                    unsigned short* __restrict__ dst, int n) {
  int i = (blockIdx.x * 256 + threadIdx.x) * 4;
  if (i >= n) return;
  int4 v = *(const int4*)(src + i);
  union { unsigned short us[4]; unsigned long long ll; } o;
  o.us[0] = f2bf((float)v.x);
  o.us[1] = f2bf((float)v.y);
  o.us[2] = f2bf((float)v.z);
  o.us[3] = f2bf((float)v.w);
  *(unsigned long long*)(dst + i) = o.ll;
}

// ---------------- 128x128 bf16 GEMM mainloop (m97 structure) -----------------
DI void gemm128(const unsigned short* __restrict__ A, const unsigned short* __restrict__ Bt,
                int m0, int n0, f32x4 (&acc)[4][4],
                unsigned short (&As)[128][32], unsigned short (&Bs)[128][32]) {
  const int tid = threadIdx.x;
  const int lane = tid & 63, w = tid >> 6;
  const int r = lane & 15, g = lane >> 4;
  const int wm = (w >> 1) * 64, wn = (w & 1) * 64;
  const int lrow = lane >> 2, lcol = (lane & 3) * 8;
  const unsigned short* ag = A + (size_t)(m0 + w * 32 + lrow) * Ec + lcol;
  const unsigned short* bg = Bt + (size_t)(n0 + w * 32 + lrow) * Ec + lcol;
  unsigned short* la0 = &As[w * 32][0];
  unsigned short* la1 = &As[w * 32 + 16][0];
  unsigned short* lb0 = &Bs[w * 32][0];
  unsigned short* lb1 = &Bs[w * 32 + 16][0];

  for (int k0 = 0; k0 < Ec; k0 += 32) {
    __syncthreads();
    gl_lds16(ag + k0, la0);
    gl_lds16(ag + (size_t)16 * Ec + k0, la1);
    gl_lds16(bg + k0, lb0);
    gl_lds16(bg + (size_t)16 * Ec + k0, lb1);
    __syncthreads();
    short8 af[4], bf[4];
#pragma unroll
    for (int mi = 0; mi < 4; ++mi) af[mi] = *(const short8*)&As[wm + mi * 16 + r][g * 8];
#pragma unroll
    for (int ni = 0; ni < 4; ++ni) bf[ni] = *(const short8*)&Bs[wn + ni * 16 + r][g * 8];
#pragma unroll
    for (int mi = 0; mi < 4; ++mi)
#pragma unroll
      for (int ni = 0; ni < 4; ++ni)
        acc[mi][ni] = __builtin_amdgcn_mfma_f32_16x16x32_bf16(af[mi], bf[ni], acc[mi][ni], 0, 0, 0);
  }
}

// ---------------- kernel 1: QKV GEMM + scale/bias + scatter to Q/K/V ---------
// K is written with an XOR column swizzle (col ^= (row&7)<<3) so the attention
// kernel can global_load_lds it linearly and ds_read_b128 conflict-free.
__global__ __launch_bounds__(256) void gemm_qkv(
    const unsigned short* __restrict__ Xbf, const unsigned short* __restrict__ Wq,
    const float* __restrict__ qsc, const float* __restrict__ qkvs, const float* __restrict__ qkvb,
    float* __restrict__ Qf, unsigned short* __restrict__ Khi, unsigned short* __restrict__ Klo,
    unsigned short* __restrict__ Vt) {
  __shared__ __align__(16) unsigned short As[128][32];
  __shared__ __align__(16) unsigned short Bs[128][32];
  f32x4 acc[4][4];
#pragma unroll
  for (int i = 0; i < 4; ++i)
#pragma unroll
    for (int j = 0; j < 4; ++j)
#pragma unroll
      for (int k = 0; k < 4; ++k) acc[i][j][k] = 0.f;
  const int m0 = blockIdx.y * 128, n0 = blockIdx.x * 128;
  gemm128(Xbf, Wq, m0, n0, acc, As, Bs);

  const int lane = threadIdx.x & 63, w = threadIdx.x >> 6;
  const int r = lane & 15, g = lane >> 4;
  const int wm = (w >> 1) * 64, wn = (w & 1) * 64;
  const int which = n0 / Ec;   // uniform per block (Ec % 128 == 0)
#pragma unroll
  for (int mi = 0; mi < 4; ++mi)
#pragma unroll
    for (int ni = 0; ni < 4; ++ni)
#pragma unroll
      for (int j = 0; j < 4; ++j) {
        int row = m0 + wm + mi * 16 + g * 4 + j;
        if (row >= Mc) continue;
        int col = n0 + wn + ni * 16 + r;
        float v = acc[mi][ni][j] * qsc[row] * qkvs[col] + qkvb[col];
        int bb = row / Sc, ss = row - bb * Sc;
        int ce = col - which * Ec;
        int hh = ce >> 7, dd = ce & 127;
        size_t bh = (size_t)(bb * NHc + hh);
        if (which == 0) {
          Qf[(bh * Spad + ss) * Dc + dd] = v;
        } else if (which == 1) {
          unsigned short hi = f2bf(v);
          unsigned short lo = f2bf(v - bf2f(hi));
          int dds = dd ^ ((ss & 7) << 3);     // bank-conflict swizzle
          size_t idx = (bh * Spad + ss) * Dc + dds;
          Khi[idx] = hi;
          Klo[idx] = lo;
        } else {
          Vt[(bh * Dc + dd) * Spad + ss] = f2bf(v);
        }
      }
}

// ---------------- kernel 2: flash attention -------------------------------
// block = 4 waves; wave w handles 16 q rows; one (b,h) per blockIdx.y.
// K hi/lo staged in LDS (double-buffered, prefetched one tile ahead via
// global_load_lds); V issued early to registers; single barrier per tile.
__global__ __launch_bounds__(256) void attn_kernel(
    const float* __restrict__ Qf, const unsigned short* __restrict__ Khi,
    const unsigned short* __restrict__ Klo, const unsigned short* __restrict__ Vt,
    float* __restrict__ Out) {
  __shared__ __align__(16) unsigned short KhiL[2][32][128];   // 16 KB
  __shared__ __align__(16) unsigned short KloL[2][32][128];   // 16 KB
  __shared__ unsigned short Pl[4][16][40];                    // 5 KB
  const int tid = threadIdx.x, lane = tid & 63, w = tid >> 6;
  const int r = lane & 15, g = lane >> 4;
  const int bh = blockIdx.y, qb = blockIdx.x;
  const int b = bh / NHc, h = bh - b * NHc;
  const float* Qb = Qf + (size_t)bh * Spad * Dc;
  const unsigned short* Khb = Khi + (size_t)bh * Spad * Dc;
  const unsigned short* Klb = Klo + (size_t)bh * Spad * Dc;
  const unsigned short* Vb = Vt + (size_t)bh * Dc * Spad;
  const int q0 = qb * 64 + w * 16;

  // staging geometry: wave w stages rows [w*8, w*8+8) of the 32-row tile;
  // each gl_lds issue covers 4 rows (64 lanes * 16B = 1KB).
  const int srow = (lane >> 4);            // 0..3 row within 4-row issue
  const int scol = (lane & 15) * 8;        // 16B chunk within 256B row
  auto stage = [&](int t_tile, int buf) {
    const unsigned short* s0 = Khb + (size_t)(t_tile + w * 8 + srow) * Dc + scol;
    const unsigned short* s1 = Klb + (size_t)(t_tile + w * 8 + srow) * Dc + scol;
    gl_lds16(s0, &KhiL[buf][w * 8][0]);
    gl_lds16(s0 + (size_t)4 * Dc, &KhiL[buf][w * 8 + 4][0]);
    gl_lds16(s1, &KloL[buf][w * 8][0]);
    gl_lds16(s1 + (size_t)4 * Dc, &KloL[buf][w * 8 + 4][0]);
  };

  // hoist Q (scaled) as hi/lo bf16 fragments
  short8 qhi[4], qlo[4];
  {
    const float* qp = Qb + (size_t)(q0 + r) * Dc + g * 8;
#pragma unroll
    for (int kf = 0; kf < 4; ++kf) {
      float4 v0 = *(const float4*)(qp + kf * 32);
      float4 v1 = *(const float4*)(qp + kf * 32 + 4);
      float f[8] = {v0.x, v0.y, v0.z, v0.w, v1.x, v1.y, v1.z, v1.w};
#pragma unroll
      for (int j = 0; j < 8; ++j) {
        float s = f[j] * ATTN_SCALE;
        unsigned short hi = f2bf(s);
        qhi[kf][j] = (short)hi;
        qlo[kf][j] = (short)f2bf(s - bf2f(hi));
      }
    }
  }

  f32x4 accO[8];
#pragma unroll
  for (int df = 0; df < 8; ++df)
#pragma unroll
    for (int j = 0; j < 4; ++j) accO[df][j] = 0.f;
  float m_run[4], l_run[4];
#pragma unroll
  for (int j = 0; j < 4; ++j) { m_run[j] = -INFINITY; l_run[j] = 0.f; }

  int cur = 0;
  stage(0, 0);
  __syncthreads();                    // drain prologue stage

  for (int t0 = 0; t0 < 1056; t0 += 32) {
    // prefetch next K tile (rows t0+32..t0+63 <= 1087 < Spad: always in-bounds)
    stage(t0 + 32, cur ^ 1);

    // V tile early to registers (consumed after softmax; compiler inserts vmcnt)
    short8 vreg[8];
#pragma unroll
    for (int df = 0; df < 8; ++df)
      vreg[df] = *(const short8*)(Vb + (size_t)(df * 16 + r) * Spad + t0 + g * 8);

    // QK^T from LDS (swizzled reads, 2-way conflict = free)
    f32x4 sacc[2];
#pragma unroll
    for (int nb = 0; nb < 2; ++nb)
#pragma unroll
      for (int j = 0; j < 4; ++j) sacc[nb][j] = 0.f;
#pragma unroll
    for (int nb = 0; nb < 2; ++nb) {
      const int lr = nb * 16 + r;
      const int sw = (r & 7) << 3;
#pragma unroll
      for (int kf = 0; kf < 4; ++kf) {
        const int c = (g * 8 + kf * 32) ^ sw;
        short8 bh_ = *(const short8*)&KhiL[cur][lr][c];
        short8 bl_ = *(const short8*)&KloL[cur][lr][c];
        sacc[nb] = __builtin_amdgcn_mfma_f32_16x16x32_bf16(qhi[kf], bh_, sacc[nb], 0, 0, 0);
        sacc[nb] = __builtin_amdgcn_mfma_f32_16x16x32_bf16(qlo[kf], bh_, sacc[nb], 0, 0, 0);
        sacc[nb] = __builtin_amdgcn_mfma_f32_16x16x32_bf16(qhi[kf], bl_, sacc[nb], 0, 0, 0);
      }
      const int tr = t0 + nb * 16 + r;
      if (tr >= Sc) {
#pragma unroll
        for (int j = 0; j < 4; ++j) sacc[nb][j] = -1e30f;
      }
    }

    // online softmax: rows are (g*4+j); reduce across the 16-lane group
    float mt[4];
#pragma unroll
    for (int j = 0; j < 4; ++j) mt[j] = fmaxf(sacc[0][j], sacc[1][j]);
#pragma unroll
    for (int d = 1; d < 16; d <<= 1)
#pragma unroll
      for (int j = 0; j < 4; ++j) mt[j] = fmaxf(mt[j], __shfl_xor(mt[j], d, 64));
    float p0[4], p1[4], ps[4], resc[4];
#pragma unroll
    for (int j = 0; j < 4; ++j) {
      float mn = fmaxf(m_run[j], mt[j]);
      resc[j] = __expf(m_run[j] - mn);
      m_run[j] = mn;
      p0[j] = __expf(sacc[0][j] - mn);
      p1[j] = __expf(sacc[1][j] - mn);
      ps[j] = p0[j] + p1[j];
    }
#pragma unroll
    for (int d = 1; d < 16; d <<= 1)
#pragma unroll
      for (int j = 0; j < 4; ++j) ps[j] += __shfl_xor(ps[j], d, 64);
#pragma unroll
    for (int j = 0; j < 4; ++j) l_run[j] = l_run[j] * resc[j] + ps[j];
#pragma unroll
    for (int df = 0; df < 8; ++df)
#pragma unroll
      for (int j = 0; j < 4; ++j) accO[df][j] *= resc[j];

    // transpose P (C-layout -> A-layout) through per-wave LDS tile: no block
    // barrier needed, only wave-local lgkm drain + sched fence (rule #18).
#pragma unroll
    for (int j = 0; j < 4; ++j) {
      Pl[w][g * 4 + j][r] = f2bf(p0[j]);
      Pl[w][g * 4 + j][16 + r] = f2bf(p1[j]);
    }
    asm volatile("s_waitcnt lgkmcnt(0)" ::: "memory");
    __builtin_amdgcn_sched_barrier(0);
    short8 pa = *(const short8*)&Pl[w][r][g * 8];
#pragma unroll
    for (int df = 0; df < 8; ++df)
      accO[df] = __builtin_amdgcn_mfma_f32_16x16x32_bf16(pa, vreg[df], accO[df], 0, 0, 0);

    __syncthreads();                  // drain next-tile stage; sync buffer swap
    cur ^= 1;
  }

  // epilogue: divide by l, store to Out[m][h*128+d]
#pragma unroll
  for (int j = 0; j < 4; ++j) {
    int sr_ = q0 + g * 4 + j;
    if (sr_ < Sc) {
      float inv = 1.f / l_run[j];
      float* op = Out + ((size_t)(b * Sc + sr_)) * Ec + h * Dc + r;
#pragma unroll
      for (int df = 0; df < 8; ++df) op[df * 16] = accO[df][j] * inv;
    }
  }
}

// ---------------- kernel 3: per-row absmax + quantize ------------------------
__global__ __launch_bounds__(256) void rowquant(const float* __restrict__ Out,
                                                unsigned short* __restrict__ Q2,
                                                float* __restrict__ S2v) {
  const int m = blockIdx.x;
  const int t = threadIdx.x;
  const float* row = Out + (size_t)m * Ec;
  float am = 0.f;
  for (int i = t * 4; i < Ec; i += 1024) {
    float4 v = *(const float4*)(row + i);
    am = fmaxf(am, fmaxf(fmaxf(fabsf(v.x), fabsf(v.y)), fmaxf(fabsf(v.z), fabsf(v.w))));
  }
#pragma unroll
  for (int d = 1; d < 64; d <<= 1) am = fmaxf(am, __shfl_xor(am, d, 64));
  __shared__ float red[4];
  if ((t & 63) == 0) red[t >> 6] = am;
  __syncthreads();
  am = fmaxf(fmaxf(red[0], red[1]), fmaxf(red[2], red[3]));
  float s2 = am / 127.f;
  if (!(s2 > 0.f)) s2 = 1.f;
  for (int i = t * 4; i < Ec; i += 1024) {
    float4 v = *(const float4*)(row + i);
    ushort4 q;
    q.x = f2bf(fminf(127.f, fmaxf(-128.f, rintf(v.x / s2))));
    q.y = f2bf(fminf(127.f, fmaxf(-128.f, rintf(v.y / s2))));
    q.z = f2bf(fminf(127.f, fmaxf(-128.f, rintf(v.z / s2))));
    q.w = f2bf(fminf(127.f, fmaxf(-128.f, rintf(v.w / s2))));
    *(ushort4*)(Q2 + (size_t)m * Ec + i) = q;
  }
  if (t == 0) S2v[m] = s2;
}

// ---------------- kernel 4: proj GEMM + scale/bias ---------------------------
__global__ __launch_bounds__(256) void gemm_proj(
    const unsigned short* __restrict__ Q2, const unsigned short* __restrict__ Wp,
    const float* __restrict__ S2v, const float* __restrict__ ps, const float* __restrict__ pb,
    float* __restrict__ Y) {
  __shared__ __align__(16) unsigned short As[128][32];
  __shared__ __align__(16) unsigned short Bs[128][32];
  f32x4 acc[4][4];
#pragma unroll
  for (int i = 0; i < 4; ++i)
#pragma unroll
    for (int j = 0; j < 4; ++j)
#pragma unroll
      for (int k = 0; k < 4; ++k) acc[i][j][k] = 0.f;
  const int m0 = blockIdx.y * 128, n0 = blockIdx.x * 128;
  gemm128(Q2, Wp, m0, n0, acc, As, Bs);

  const int lane = threadIdx.x & 63, w = threadIdx.x >> 6;
  const int r = lane & 15, g = lane >> 4;
  const int wm = (w >> 1) * 64, wn = (w & 1) * 64;
#pragma unroll
  for (int mi = 0; mi < 4; ++mi)
#pragma unroll
    for (int ni = 0; ni < 4; ++ni)
#pragma unroll
      for (int j = 0; j < 4; ++j) {
        int row = m0 + wm + mi * 16 + g * 4 + j;
        if (row >= Mc) continue;
        int col = n0 + wn + ni * 16 + r;
        Y[(size_t)row * Ec + col] = acc[mi][ni][j] * S2v[row] * ps[col] + pb[col];
      }
}

// ---------------- launch -----------------------------------------------------
extern "C" void kernel_launch(void* const* d_in, const int* in_sizes, int n_in,
                              void* d_out, int out_size, void* d_ws, size_t ws_size,
                              hipStream_t stream) {
  const int* hs = (const int*)d_in[0];
  const float* qscale = (const float*)d_in[1];
  const int* qkvw = (const int*)d_in[2];
  const float* qkvs = (const float*)d_in[3];
  const float* qkvb = (const float*)d_in[4];
  const int* projw = (const int*)d_in[5];
  const float* projs = (const float*)d_in[6];
  const float* projb = (const float*)d_in[7];
  float* y = (float*)d_out;

  char* p = (char*)d_ws;
  auto carve = [&](size_t bytes) {
    char* q = p;
    p += (bytes + 255) & ~(size_t)255;
    return q;
  };
  unsigned short* Xbf = (unsigned short*)carve((size_t)Mpad * Ec * 2);   // 27.0 MB
  unsigned short* Wq = (unsigned short*)carve((size_t)N1c * Ec * 2);     // 61.4 MB
  unsigned short* Wp = (unsigned short*)carve((size_t)Ec * Ec * 2);      // 20.5 MB
  float* Qf = (float*)carve((size_t)BHc * Spad * Dc * 4);                // 59.0 MB
  unsigned short* Khi = (unsigned short*)carve((size_t)BHc * Spad * Dc * 2);  // 29.5 MB
  unsigned short* Klo = (unsigned short*)carve((size_t)BHc * Spad * Dc * 2);  // 29.5 MB
  unsigned short* Vt = (unsigned short*)carve((size_t)BHc * Dc * Spad * 2);   // 29.5 MB
  float* Out = (float*)Wq;           // Wq dead after gemm_qkv; 52.5 MB <= 61.4 MB
  unsigned short* Q2 = Xbf;          // Xbf dead after gemm_qkv; same padding semantics
  float* S2v = (float*)carve((size_t)Mpad * 4);

  // zero the padding rows of Xbf (also serves as Q2's padding later)
  hipMemsetAsync(Xbf + (size_t)Mc * Ec, 0, (size_t)(Mpad - Mc) * Ec * 2, stream);

  cvt_i32_bf16<<<(Mc * Ec / 4 + 255) / 256, 256, 0, stream>>>(hs, Xbf, Mc * Ec);
  cvt_i32_bf16<<<(N1c * Ec / 4) / 256, 256, 0, stream>>>(qkvw, Wq, N1c * Ec);
  cvt_i32_bf16<<<(Ec * Ec / 4) / 256, 256, 0, stream>>>(projw, Wp, Ec * Ec);

  gemm_qkv<<<dim3(N1c / 128, Mpad / 128), 256, 0, stream>>>(Xbf, Wq, qscale, qkvs, qkvb,
                                                            Qf, Khi, Klo, Vt);
  attn_kernel<<<dim3(17, BHc), 256, 0, stream>>>(Qf, Khi, Klo, Vt, Out);
  rowquant<<<Mc, 256, 0, stream>>>(Out, Q2, S2v);
  gemm_proj<<<dim3(Ec / 128, Mpad / 128), 256, 0, stream>>>(Q2, Wp, S2v, projs, projb, y);
}

// Round 5
// 936.048 us; speedup vs baseline: 2.0881x; 1.3188x over previous
//
#include <hip/hip_runtime.h>

typedef __attribute__((ext_vector_type(8))) short short8;
typedef __attribute__((ext_vector_type(4))) float f32x4;
typedef __attribute__((ext_vector_type(4))) int i32x4;

#define DI __device__ __forceinline__

constexpr int Bc = 4, Sc = 1025, Ec = 3200, NHc = 25, Dc = 128;
constexpr int Mc = Bc * Sc;          // 4100
constexpr int Mpad = 4224;           // 33 * 128
constexpr int N1c = 3 * Ec;          // 9600
constexpr int Spad = 1152;           // >= 1088 (staging reads up to 1087); mult of 128
constexpr int BHc = Bc * NHc;        // 100
constexpr float ATTN_SCALE = 0.08838834764831845f;  // 128^-0.5

DI unsigned short f2bf(float f) {
  union { float f; unsigned u; } x; x.f = f;
  unsigned r = x.u + 0x7fffu + ((x.u >> 16) & 1u);   // RNE
  return (unsigned short)(r >> 16);
}
DI float bf2f(unsigned short h) {
  union { unsigned u; float f; } x; x.u = (unsigned)h << 16;
  return x.f;
}

// async global->LDS, 16B per lane; LDS dest = wave-uniform base + lane*16 (linear)
DI void gl_lds16(const void* g, void* l) {
  __builtin_amdgcn_global_load_lds(
      (const __attribute__((address_space(1))) unsigned int*)g,
      (__attribute__((address_space(3))) unsigned int*)l, 16, 0, 0);
}

// bijective XCD-aware remap (m204): contiguous wg runs land on one XCD's L2
DI int xcd_remap(int orig, int nwg) {
  int xcd = orig & 7;
  int q = nwg >> 3, rr = nwg & 7;
  int base = (xcd < rr) ? xcd * (q + 1) : rr * (q + 1) + (xcd - rr) * q;
  return base + (orig >> 3);
}

// ---------------- int32 -> int8 pack with chunk swizzle ----------------------
// Row layout (cols = 3200 = 200 x 16B chunks = 50 x 64B groups): physical
// chunk c of each 64B group holds logical chunk c ^ ((row>>1)&3). The GEMM
// stages these bytes verbatim via global_load_lds and un-XORs on ds_read,
// making the [128][64] LDS tile 2-way-conflict-free (free per m136).
__global__ __launch_bounds__(256) void pack_i8_swz(const int* __restrict__ src,
                                                   signed char* __restrict__ dst, int nchunks) {
  int gid = blockIdx.x * 256 + threadIdx.x;
  if (gid >= nchunks) return;
  int row = gid / 200, ch = gid - row * 200;
  int gg = ch >> 2, c = ch & 3;
  int lc = c ^ ((row >> 1) & 3);
  const int* s = src + (size_t)row * Ec + gg * 64 + lc * 16;
  int4 a0 = *(const int4*)(s);
  int4 a1 = *(const int4*)(s + 4);
  int4 a2 = *(const int4*)(s + 8);
  int4 a3 = *(const int4*)(s + 12);
  union { signed char b[16]; i32x4 v; } pk;
  pk.b[0] = (signed char)a0.x;  pk.b[1] = (signed char)a0.y;
  pk.b[2] = (signed char)a0.z;  pk.b[3] = (signed char)a0.w;
  pk.b[4] = (signed char)a1.x;  pk.b[5] = (signed char)a1.y;
  pk.b[6] = (signed char)a1.z;  pk.b[7] = (signed char)a1.w;
  pk.b[8] = (signed char)a2.x;  pk.b[9] = (signed char)a2.y;
  pk.b[10] = (signed char)a2.z; pk.b[11] = (signed char)a2.w;
  pk.b[12] = (signed char)a3.x; pk.b[13] = (signed char)a3.y;
  pk.b[14] = (signed char)a3.z; pk.b[15] = (signed char)a3.w;
  *(i32x4*)(dst + (size_t)row * Ec + gg * 64 + c * 16) = pk.v;
}

// ---------------- 128x128 i8 GEMM mainloop (m97 structure, BK=64) ------------
// C = A * Bt^T over K=3200, exact i32 accumulation. 4 waves as 2x2 grid of
// 64x64 sub-tiles; staging via global_load_lds width-16 (linear LDS).
DI void gemm128_i8(const signed char* __restrict__ A, const signed char* __restrict__ Bt,
                   int m0, int n0, i32x4 (&acc)[4][4],
                   signed char (&As)[128][64], signed char (&Bs)[128][64]) {
  const int tid = threadIdx.x;
  const int lane = tid & 63, w = tid >> 6;
  const int r = lane & 15, g = lane >> 4;
  const int wm = (w >> 1) * 64, wn = (w & 1) * 64;
  // staging: each issue covers 16 rows (64 lanes x 16B); wave w covers rows [w*32, w*32+32)
  const int lrow = lane >> 2, lcol = (lane & 3) * 16;
  const signed char* ag = A + (size_t)(m0 + w * 32 + lrow) * Ec + lcol;
  const signed char* bg = Bt + (size_t)(n0 + w * 32 + lrow) * Ec + lcol;
  signed char* la0 = &As[w * 32][0];
  signed char* la1 = &As[w * 32 + 16][0];
  signed char* lb0 = &Bs[w * 32][0];
  signed char* lb1 = &Bs[w * 32 + 16][0];
  const int ca = (g ^ ((r >> 1) & 3)) * 16;   // un-swizzle on read

  for (int k0 = 0; k0 < Ec; k0 += 64) {
    __syncthreads();
    gl_lds16(ag + k0, la0);
    gl_lds16(ag + (size_t)16 * Ec + k0, la1);
    gl_lds16(bg + k0, lb0);
    gl_lds16(bg + (size_t)16 * Ec + k0, lb1);
    __syncthreads();
    i32x4 af[4], bf[4];
#pragma unroll
    for (int mi = 0; mi < 4; ++mi) af[mi] = *(const i32x4*)&As[wm + mi * 16 + r][ca];
#pragma unroll
    for (int ni = 0; ni < 4; ++ni) bf[ni] = *(const i32x4*)&Bs[wn + ni * 16 + r][ca];
#pragma unroll
    for (int mi = 0; mi < 4; ++mi)
#pragma unroll
      for (int ni = 0; ni < 4; ++ni)
        acc[mi][ni] = __builtin_amdgcn_mfma_i32_16x16x64_i8(af[mi], bf[ni], acc[mi][ni], 0, 0, 0);
  }
}

// ---------------- kernel 1: QKV GEMM + scale/bias + scatter to Q/K/V ---------
__global__ __launch_bounds__(256) void gemm_qkv(
    const signed char* __restrict__ Xq, const signed char* __restrict__ Wq,
    const float* __restrict__ qsc, const float* __restrict__ qkvs, const float* __restrict__ qkvb,
    float* __restrict__ Qf, unsigned short* __restrict__ Khi, unsigned short* __restrict__ Klo,
    unsigned short* __restrict__ Vt) {
  __shared__ __align__(16) signed char As[128][64];
  __shared__ __align__(16) signed char Bs[128][64];
  i32x4 acc[4][4];
#pragma unroll
  for (int i = 0; i < 4; ++i)
#pragma unroll
    for (int j = 0; j < 4; ++j)
#pragma unroll
      for (int k = 0; k < 4; ++k) acc[i][j][k] = 0;
  const int nbx = N1c / 128;                       // 75
  const int wg = xcd_remap(blockIdx.y * nbx + blockIdx.x, nbx * (Mpad / 128));
  const int m0 = (wg / nbx) * 128, n0 = (wg % nbx) * 128;
  gemm128_i8(Xq, Wq, m0, n0, acc, As, Bs);

  const int lane = threadIdx.x & 63, w = threadIdx.x >> 6;
  const int r = lane & 15, g = lane >> 4;
  const int wm = (w >> 1) * 64, wn = (w & 1) * 64;
  const int which = n0 / Ec;   // uniform per block (Ec % 128 == 0)
#pragma unroll
  for (int mi = 0; mi < 4; ++mi)
#pragma unroll
    for (int ni = 0; ni < 4; ++ni)
#pragma unroll
      for (int j = 0; j < 4; ++j) {
        int row = m0 + wm + mi * 16 + g * 4 + j;
        if (row >= Mc) continue;
        int col = n0 + wn + ni * 16 + r;
        float v = (float)acc[mi][ni][j] * qsc[row] * qkvs[col] + qkvb[col];
        int bb = row / Sc, ss = row - bb * Sc;
        int ce = col - which * Ec;
        int hh = ce >> 7, dd = ce & 127;
        size_t bh = (size_t)(bb * NHc + hh);
        if (which == 0) {
          Qf[(bh * Spad + ss) * Dc + dd] = v;
        } else if (which == 1) {
          unsigned short hi = f2bf(v);
          unsigned short lo = f2bf(v - bf2f(hi));
          int dds = dd ^ ((ss & 7) << 3);     // attn LDS bank-conflict swizzle
          size_t idx = (bh * Spad + ss) * Dc + dds;
          Khi[idx] = hi;
          Klo[idx] = lo;
        } else {
          Vt[(bh * Dc + dd) * Spad + ss] = f2bf(v);
        }
      }
}

// ---------------- kernel 2: flash attention -------------------------------
// block = 4 waves; wave w handles 16 q rows. K hi/lo staged in LDS (double-
// buffered, prefetched one tile ahead); V issued early to regs; 1 barrier/tile.
__global__ __launch_bounds__(256) void attn_kernel(
    const float* __restrict__ Qf, const unsigned short* __restrict__ Khi,
    const unsigned short* __restrict__ Klo, const unsigned short* __restrict__ Vt,
    float* __restrict__ Out) {
  __shared__ __align__(16) unsigned short KhiL[2][32][128];   // 16 KB
  __shared__ __align__(16) unsigned short KloL[2][32][128];   // 16 KB
  __shared__ unsigned short Pl[4][16][40];                    // 5 KB
  const int tid = threadIdx.x, lane = tid & 63, w = tid >> 6;
  const int r = lane & 15, g = lane >> 4;
  const int wg = xcd_remap(blockIdx.y * 17 + blockIdx.x, 17 * BHc);
  const int bh = wg / 17, qb = wg - bh * 17;
  const int b = bh / NHc, h = bh - b * NHc;
  const float* Qb = Qf + (size_t)bh * Spad * Dc;
  const unsigned short* Khb = Khi + (size_t)bh * Spad * Dc;
  const unsigned short* Klb = Klo + (size_t)bh * Spad * Dc;
  const unsigned short* Vb = Vt + (size_t)bh * Dc * Spad;
  const int q0 = qb * 64 + w * 16;

  const int srow = (lane >> 4);            // 0..3 row within 4-row issue
  const int scol = (lane & 15) * 8;        // 16B chunk within 256B row
  auto stage = [&](int t_tile, int buf) {
    const unsigned short* s0 = Khb + (size_t)(t_tile + w * 8 + srow) * Dc + scol;
    const unsigned short* s1 = Klb + (size_t)(t_tile + w * 8 + srow) * Dc + scol;
    gl_lds16(s0, &KhiL[buf][w * 8][0]);
    gl_lds16(s0 + (size_t)4 * Dc, &KhiL[buf][w * 8 + 4][0]);
    gl_lds16(s1, &KloL[buf][w * 8][0]);
    gl_lds16(s1 + (size_t)4 * Dc, &KloL[buf][w * 8 + 4][0]);
  };

  // hoist Q (scaled) as hi/lo bf16 fragments
  short8 qhi[4], qlo[4];
  {
    const float* qp = Qb + (size_t)(q0 + r) * Dc + g * 8;
#pragma unroll
    for (int kf = 0; kf < 4; ++kf) {
      float4 v0 = *(const float4*)(qp + kf * 32);
      float4 v1 = *(const float4*)(qp + kf * 32 + 4);
      float f[8] = {v0.x, v0.y, v0.z, v0.w, v1.x, v1.y, v1.z, v1.w};
#pragma unroll
      for (int j = 0; j < 8; ++j) {
        float s = f[j] * ATTN_SCALE;
        unsigned short hi = f2bf(s);
        qhi[kf][j] = (short)hi;
        qlo[kf][j] = (short)f2bf(s - bf2f(hi));
      }
    }
  }

  f32x4 accO[8];
#pragma unroll
  for (int df = 0; df < 8; ++df)
#pragma unroll
    for (int j = 0; j < 4; ++j) accO[df][j] = 0.f;
  float m_run[4], l_run[4];
#pragma unroll
  for (int j = 0; j < 4; ++j) { m_run[j] = -INFINITY; l_run[j] = 0.f; }

  int cur = 0;
  stage(0, 0);
  __syncthreads();                    // drain prologue stage

  for (int t0 = 0; t0 < 1056; t0 += 32) {
    stage(t0 + 32, cur ^ 1);          // prefetch next K tile (rows <= 1087 < Spad)

    short8 vreg[8];                   // V tile early (compiler inserts vmcnt)
#pragma unroll
    for (int df = 0; df < 8; ++df)
      vreg[df] = *(const short8*)(Vb + (size_t)(df * 16 + r) * Spad + t0 + g * 8);

    f32x4 sacc[2];
#pragma unroll
    for (int nb = 0; nb < 2; ++nb)
#pragma unroll
      for (int j = 0; j < 4; ++j) sacc[nb][j] = 0.f;
#pragma unroll
    for (int nb = 0; nb < 2; ++nb) {
      const int lr = nb * 16 + r;
      const int sw = (r & 7) << 3;
#pragma unroll
      for (int kf = 0; kf < 4; ++kf) {
        const int c = (g * 8 + kf * 32) ^ sw;
        short8 bh_ = *(const short8*)&KhiL[cur][lr][c];
        short8 bl_ = *(const short8*)&KloL[cur][lr][c];
        sacc[nb] = __builtin_amdgcn_mfma_f32_16x16x32_bf16(qhi[kf], bh_, sacc[nb], 0, 0, 0);
        sacc[nb] = __builtin_amdgcn_mfma_f32_16x16x32_bf16(qlo[kf], bh_, sacc[nb], 0, 0, 0);
        sacc[nb] = __builtin_amdgcn_mfma_f32_16x16x32_bf16(qhi[kf], bl_, sacc[nb], 0, 0, 0);
      }
      const int tr = t0 + nb * 16 + r;
      if (tr >= Sc) {
#pragma unroll
        for (int j = 0; j < 4; ++j) sacc[nb][j] = -1e30f;
      }
    }

    // online softmax: rows are (g*4+j); reduce across the 16-lane group
    float mt[4];
#pragma unroll
    for (int j = 0; j < 4; ++j) mt[j] = fmaxf(sacc[0][j], sacc[1][j]);
#pragma unroll
    for (int d = 1; d < 16; d <<= 1)
#pragma unroll
      for (int j = 0; j < 4; ++j) mt[j] = fmaxf(mt[j], __shfl_xor(mt[j], d, 64));
    float p0[4], p1[4], ps[4], resc[4];
#pragma unroll
    for (int j = 0; j < 4; ++j) {
      float mn = fmaxf(m_run[j], mt[j]);
      resc[j] = __expf(m_run[j] - mn);
      m_run[j] = mn;
      p0[j] = __expf(sacc[0][j] - mn);
      p1[j] = __expf(sacc[1][j] - mn);
      ps[j] = p0[j] + p1[j];
    }
#pragma unroll
    for (int d = 1; d < 16; d <<= 1)
#pragma unroll
      for (int j = 0; j < 4; ++j) ps[j] += __shfl_xor(ps[j], d, 64);
#pragma unroll
    for (int j = 0; j < 4; ++j) l_run[j] = l_run[j] * resc[j] + ps[j];
#pragma unroll
    for (int df = 0; df < 8; ++df)
#pragma unroll
      for (int j = 0; j < 4; ++j) accO[df][j] *= resc[j];

    // transpose P (C-layout -> A-layout) through per-wave LDS tile
#pragma unroll
    for (int j = 0; j < 4; ++j) {
      Pl[w][g * 4 + j][r] = f2bf(p0[j]);
      Pl[w][g * 4 + j][16 + r] = f2bf(p1[j]);
    }
    asm volatile("s_waitcnt lgkmcnt(0)" ::: "memory");
    __builtin_amdgcn_sched_barrier(0);
    short8 pa = *(const short8*)&Pl[w][r][g * 8];
#pragma unroll
    for (int df = 0; df < 8; ++df)
      accO[df] = __builtin_amdgcn_mfma_f32_16x16x32_bf16(pa, vreg[df], accO[df], 0, 0, 0);

    __syncthreads();                  // drain next-tile stage; sync buffer swap
    cur ^= 1;
  }

  // epilogue: divide by l, store to Out[m][h*128+d]
#pragma unroll
  for (int j = 0; j < 4; ++j) {
    int sr_ = q0 + g * 4 + j;
    if (sr_ < Sc) {
      float inv = 1.f / l_run[j];
      float* op = Out + ((size_t)(b * Sc + sr_)) * Ec + h * Dc + r;
#pragma unroll
      for (int df = 0; df < 8; ++df) op[df * 16] = accO[df][j] * inv;
    }
  }
}

// ---------------- kernel 3: per-row absmax + quantize to swizzled i8 ---------
__global__ __launch_bounds__(256) void rowquant(const float* __restrict__ Out,
                                                signed char* __restrict__ Q2,
                                                float* __restrict__ S2v) {
  const int m = blockIdx.x;
  const int t = threadIdx.x;
  const float* row = Out + (size_t)m * Ec;
  float v[16];
  float am = 0.f;
  if (t < 200) {
#pragma unroll
    for (int q = 0; q < 4; ++q) {
      float4 x = *(const float4*)(row + t * 16 + q * 4);
      v[q * 4 + 0] = x.x; v[q * 4 + 1] = x.y; v[q * 4 + 2] = x.z; v[q * 4 + 3] = x.w;
    }
#pragma unroll
    for (int j = 0; j < 16; ++j) am = fmaxf(am, fabsf(v[j]));
  }
#pragma unroll
  for (int d = 1; d < 64; d <<= 1) am = fmaxf(am, __shfl_xor(am, d, 64));
  __shared__ float red[4];
  if ((t & 63) == 0) red[t >> 6] = am;
  __syncthreads();
  am = fmaxf(fmaxf(red[0], red[1]), fmaxf(red[2], red[3]));
  float s2 = am / 127.f;
  if (!(s2 > 0.f)) s2 = 1.f;
  if (t < 200) {
    float inv = 1.f / s2;
    union { signed char b[16]; i32x4 iv; } pk;
#pragma unroll
    for (int j = 0; j < 16; ++j) {
      float q = fminf(127.f, fmaxf(-128.f, rintf(v[j] * inv)));
      pk.b[j] = (signed char)(int)q;
    }
    int gg = t >> 2, c = t & 3;
    *(i32x4*)(Q2 + (size_t)m * Ec + gg * 64 + (c ^ ((m >> 1) & 3)) * 16) = pk.iv;
  }
  if (t == 0) S2v[m] = s2;
}

// ---------------- kernel 4: proj GEMM + scale/bias ---------------------------
__global__ __launch_bounds__(256) void gemm_proj(
    const signed char* __restrict__ Q2, const signed char* __restrict__ Wp,
    const float* __restrict__ S2v, const float* __restrict__ ps, const float* __restrict__ pb,
    float* __restrict__ Y) {
  __shared__ __align__(16) signed char As[128][64];
  __shared__ __align__(16) signed char Bs[128][64];
  i32x4 acc[4][4];
#pragma unroll
  for (int i = 0; i < 4; ++i)
#pragma unroll
    for (int j = 0; j < 4; ++j)
#pragma unroll
      for (int k = 0; k < 4; ++k) acc[i][j][k] = 0;
  const int nbx = Ec / 128;                        // 25
  const int wg = xcd_remap(blockIdx.y * nbx + blockIdx.x, nbx * (Mpad / 128));
  const int m0 = (wg / nbx) * 128, n0 = (wg % nbx) * 128;
  gemm128_i8(Q2, Wp, m0, n0, acc, As, Bs);

  const int lane = threadIdx.x & 63, w = threadIdx.x >> 6;
  const int r = lane & 15, g = lane >> 4;
  const int wm = (w >> 1) * 64, wn = (w & 1) * 64;
#pragma unroll
  for (int mi = 0; mi < 4; ++mi)
#pragma unroll
    for (int ni = 0; ni < 4; ++ni)
#pragma unroll
      for (int j = 0; j < 4; ++j) {
        int row = m0 + wm + mi * 16 + g * 4 + j;
        if (row >= Mc) continue;
        int col = n0 + wn + ni * 16 + r;
        Y[(size_t)row * Ec + col] = (float)acc[mi][ni][j] * S2v[row] * ps[col] + pb[col];
      }
}

// ---------------- launch -----------------------------------------------------
extern "C" void kernel_launch(void* const* d_in, const int* in_sizes, int n_in,
                              void* d_out, int out_size, void* d_ws, size_t ws_size,
                              hipStream_t stream) {
  const int* hs = (const int*)d_in[0];
  const float* qscale = (const float*)d_in[1];
  const int* qkvw = (const int*)d_in[2];
  const float* qkvs = (const float*)d_in[3];
  const float* qkvb = (const float*)d_in[4];
  const int* projw = (const int*)d_in[5];
  const float* projs = (const float*)d_in[6];
  const float* projb = (const float*)d_in[7];
  float* y = (float*)d_out;

  char* p = (char*)d_ws;
  auto carve = [&](size_t bytes) {
    char* q = p;
    p += (bytes + 255) & ~(size_t)255;
    return q;
  };
  signed char* Xq = (signed char*)carve((size_t)Mpad * Ec);              // 13.5 MB
  signed char* Wq8 = (signed char*)carve((size_t)N1c * Ec);              // 30.7 MB
  signed char* Wp8 = (signed char*)carve((size_t)Ec * Ec);               // 10.2 MB
  float* Qf = (float*)carve((size_t)BHc * Spad * Dc * 4);                // 59.0 MB
  unsigned short* Khi = (unsigned short*)carve((size_t)BHc * Spad * Dc * 2);  // 29.5 MB
  unsigned short* Klo = (unsigned short*)carve((size_t)BHc * Spad * Dc * 2);  // 29.5 MB
  unsigned short* Vt = (unsigned short*)carve((size_t)BHc * Dc * Spad * 2);   // 29.5 MB
  float* Out = (float*)carve((size_t)Mc * Ec * 4);                       // 52.5 MB
  float* S2v = (float*)carve((size_t)Mpad * 4);
  signed char* Q2 = Xq;   // Xq dead after gemm_qkv; pad rows stay zero (swz(0)=0)

  // zero the padding rows of Xq (also serves as Q2's padding later)
  hipMemsetAsync(Xq + (size_t)Mc * Ec, 0, (size_t)(Mpad - Mc) * Ec, stream);

  pack_i8_swz<<<(Mc * 200 + 255) / 256, 256, 0, stream>>>(hs, Xq, Mc * 200);
  pack_i8_swz<<<(N1c * 200) / 256, 256, 0, stream>>>(qkvw, Wq8, N1c * 200);
  pack_i8_swz<<<(Ec * 200) / 256, 256, 0, stream>>>(projw, Wp8, Ec * 200);

  gemm_qkv<<<dim3(N1c / 128, Mpad / 128), 256, 0, stream>>>(Xq, Wq8, qscale, qkvs, qkvb,
                                                            Qf, Khi, Klo, Vt);
  attn_kernel<<<dim3(17, BHc), 256, 0, stream>>>(Qf, Khi, Klo, Vt, Out);
  rowquant<<<Mc, 256, 0, stream>>>(Out, Q2, S2v);
  gemm_proj<<<dim3(Ec / 128, Mpad / 128), 256, 0, stream>>>(Q2, Wp8, S2v, projs, projb, y);
}